// Round 12
// baseline (232.180 us; speedup 1.0000x reference)
//
#include <hip/hip_runtime.h>
#include <hip/hip_fp16.h>
#include <cstdint>
#include <cstddef>

// Problem constants
#define NB 512
#define NR 1152
#define NC 8
#define NJ 10
#define NO 16
#define NJO 160   // NJ*NO

typedef unsigned int uint32;

union H2U { __half2 h; uint32 u; };

__device__ __forceinline__ uint32 packf16(float a0, float a1) {
    H2U p;
    p.h = __halves2half2(__float2half_rn(a0), __float2half_rn(a1));
    return p.u;
}
__device__ __forceinline__ float2 unpackf16(uint32 w) {
    H2U p; p.u = w;
    return __half22float2(p.h);
}

// ============================================================================
// Kernel 0: transpose x[b][r][c] -> xT[r][b][c] so uhat can stage x coalesced.
// ============================================================================
__global__ __launch_bounds__(256) void xpose_kernel(const float* __restrict__ x,
                                                    float* __restrict__ xT) {
    const int r0 = blockIdx.x * 16;
    const int b0 = blockIdx.y * 64;
    const int t  = threadIdx.x;
    __shared__ float tile[16][65][8];

    for (int i = t; i < 2048; i += 256) {
        int b = i >> 5, r = (i >> 1) & 15, h = i & 1;
        float4 v = *(const float4*)&x[(size_t)(b0 + b) * (NR * NC) + (size_t)(r0 + r) * NC + h * 4];
        *(float4*)&tile[r][b][h * 4] = v;
    }
    __syncthreads();
    for (int i = t; i < 2048; i += 256) {
        int r = i >> 7, b = (i >> 1) & 63, h = i & 1;
        float4 v = *(const float4*)&tile[r][b][h * 4];
        *(float4*)&xT[(size_t)(r0 + r) * (NB * NC) + (size_t)(b0 + b) * NC + h * 4] = v;
    }
}

// ============================================================================
// Kernel 1: u_hat -> f16 pairs in QUAD-BLOCKED row layout.
// Row (b,r) = 80 u32; slot ni = qt*20 + 2*j + d holds f16 pair
// (o = 4qt+2d, 4qt+2d+1) of capsule j.
// DS-amortized thread map (vs R9): thread owns BOTH slots of (qt,j) -- the
// 4 o's [4qt,4qt+4) -- so one 32-B x LDS broadcast feeds 32 FMA (was 16),
// halving ds_read_b128 count; result stores as one coalesced dwordx2.
// t -> (ni2 = t%40: qt = ni2/10, j = ni2%10; bg = t/40, b = bg+8k).
// ============================================================================
__global__ __launch_bounds__(320) void uhat_kernel(const float* __restrict__ xT,
                                                   const float* __restrict__ W,
                                                   uint32* __restrict__ u) {
    const int r = blockIdx.x;
    const int t = threadIdx.x;

    __shared__ float Ws[NC][NJO + 4];   // [c][jo], stride 164
    __shared__ float xs[NB][NC];

    for (int i = t; i < NJO * NC; i += 320) {
        Ws[i & 7][i >> 3] = W[(size_t)r * (NJO * NC) + i];
    }
    {
        const float4* xsrc = (const float4*)(xT + (size_t)r * (NB * NC));
        float4* xdst = (float4*)&xs[0][0];
        for (int i = t; i < (NB * NC) / 4; i += 320) xdst[i] = xsrc[i];
    }
    __syncthreads();

    const int ni2 = t % 40;
    const int bg  = t / 40;    // 0..7
    const int qt  = ni2 / 10;
    const int j   = ni2 % 10;
    const int jo0 = 16 * j + 4 * qt;        // first of 4 o's
    const int slot = qt * 20 + 2 * j;       // first of 2 u32 slots

    float w[4][8];
#pragma unroll
    for (int d = 0; d < 4; ++d)
#pragma unroll
        for (int c = 0; c < 8; ++c) w[d][c] = Ws[c][jo0 + d];

    for (int b = bg; b < NB; b += 8) {
        const float4* xp = (const float4*)xs[b];
        float4 xa = xp[0], xb = xp[1];
        float a[4];
#pragma unroll
        for (int d = 0; d < 4; ++d) {
            a[d] = w[d][0] * xa.x + w[d][1] * xa.y + w[d][2] * xa.z + w[d][3] * xa.w
                 + w[d][4] * xb.x + w[d][5] * xb.y + w[d][6] * xb.z + w[d][7] * xb.w;
        }
        uint2 p;
        p.x = packf16(a[0], a[1]);
        p.y = packf16(a[2], a[3]);
        *(uint2*)&u[(size_t)(b * NR + r) * 80 + slot] = p;
    }
}

// ============================================================================
// Merged routing kernel: ONE launch, 3 iterations. Block = one b (576 thr,
// 9 waves, 2 blocks/CU). All state (s, v, vacc) lives in LDS -- no global
// atomics, no memsets, no inter-kernel u refetch gaps.
// Per iteration: QUAD split (m = row-in-chunk, qt = o-quarter); lane loads
// its 20 contiguous u32 per row as 5 dwordx4 (16B/lane sweet spot).
// Softmax: per-j fp32 dot (unpack f16) + quad shfl combine. acc[40] fp32.
// Then 4-stage reduce-scatter over the 16 m-lanes, <=3 LDS atomics/lane,
// in-block squash, update vls/vaccl, next iteration.
// ============================================================================
__global__ __launch_bounds__(576, 2) void routing_kernel(const uint32* __restrict__ u,
                                                         float* __restrict__ outp) {
    const int b  = blockIdx.x;
    const int t  = threadIdx.x;
    const int w  = t >> 6;        // wave 0..8
    const int l  = t & 63;
    const int m  = (l >> 2) & 15; // row within chunk
    const int qt = l & 3;         // o-quarter

    __shared__ float sl[NJO];     // s accumulator
    __shared__ float vls[NJO];    // current v-sum (fp32), read by dot
    __shared__ float vaccl[NJO];  // running v0+v1 (fp32)

    for (int i = t; i < NJO; i += 576) sl[i] = 0.0f;
    __syncthreads();

    const uint32* ubase = u + (size_t)b * (NR * 80) + qt * 20;

#pragma unroll 1
    for (int it = 0; it < 3; ++it) {
        float acc[40];
#pragma unroll
        for (int i = 0; i < 40; ++i) acc[i] = 0.0f;

#pragma unroll 1
        for (int c8 = 0; c8 < 8; ++c8) {
            const int r = (w * 8 + c8) * 16 + m;
            const uint4* up = (const uint4*)(ubase + (size_t)r * 80);
            uint32 ur[20];
#pragma unroll
            for (int i = 0; i < 5; ++i) {
                uint4 q = up[i];
                ur[4 * i + 0] = q.x; ur[4 * i + 1] = q.y;
                ur[4 * i + 2] = q.z; ur[4 * i + 3] = q.w;
            }

            float cj[NJ];
            if (it == 0) {
#pragma unroll
                for (int j = 0; j < NJ; ++j) cj[j] = 0.1f;
            } else {
                float sum = 0.0f;
#pragma unroll
                for (int j = 0; j < NJ; ++j) {
                    float2 ua = unpackf16(ur[2 * j]);
                    float2 ub = unpackf16(ur[2 * j + 1]);
                    float4 vv = *(const float4*)&vls[16 * j + 4 * qt];
                    float pj = ua.x * vv.x + ua.y * vv.y + ub.x * vv.z + ub.y * vv.w;
                    pj += __shfl_xor(pj, 1);   // combine o-quarters (DPP)
                    pj += __shfl_xor(pj, 2);
                    float e = __expf(pj);      // |b_ij| <~ 70: safe in fp32
                    cj[j] = e;
                    sum += e;
                }
                float inv = 1.0f / sum;
#pragma unroll
                for (int j = 0; j < NJ; ++j) cj[j] *= inv;
            }

#pragma unroll
            for (int j = 0; j < NJ; ++j) {
                float2 ua = unpackf16(ur[2 * j]);
                float2 ub = unpackf16(ur[2 * j + 1]);
                acc[4 * j + 0] += cj[j] * ua.x;
                acc[4 * j + 1] += cj[j] * ua.y;
                acc[4 * j + 2] += cj[j] * ub.x;
                acc[4 * j + 3] += cj[j] * ub.y;
            }
        }

        // ---- reduce-scatter among the 16 same-qt lanes (masks 4,8,16,32) ----
        float a[24];
        {
            const int bit = (l >> 2) & 1;
#pragma unroll
            for (int i = 0; i < 24; ++i) {
                float lo = acc[i];
                float hi = (i + 24 < 40) ? acc[i + 24] : 0.0f;
                float send = bit ? lo : hi;
                float recv = __shfl_xor(send, 4);
                a[i] = (bit ? hi : lo) + recv;
            }
        }
#pragma unroll
        for (int st = 1; st < 4; ++st) {
            const int h = 24 >> st;              // 12,6,3
            const int bit = (l >> (2 + st)) & 1;
#pragma unroll
            for (int i = 0; i < 12; ++i) {
                if (i < h) {
                    float send = bit ? a[i] : a[i + h];
                    float recv = __shfl_xor(send, 4 << st);
                    a[i] = (bit ? a[i + h] : a[i]) + recv;
                }
            }
        }
        const int base = 3 * (__brev((uint32)m) >> 28);
#pragma unroll
        for (int i = 0; i < 3; ++i) {
            int aidx = base + i;
            if (aidx < 40) {
                int j = aidx >> 2, e = aidx & 3;
                atomicAdd(&sl[16 * j + 4 * qt + e], a[i]);
            }
        }
        __syncthreads();

        // ---- in-block squash: thread p<80 owns o-pair (2p, 2p+1) ----
        if (t < 80) {
            float2 sv = *(const float2*)&sl[2 * t];
            float sq = sv.x * sv.x + sv.y * sv.y;
#pragma unroll
            for (int off = 1; off < 8; off <<= 1) sq += __shfl_xor(sq, off, 8);
            float scale = (sq / (1.0f + sq)) * rsqrtf(sq + 1e-8f);
            float vx = sv.x * scale, vy = sv.y * scale;
            if (it == 2) {
                *(float2*)&outp[b * NJO + 2 * t] = make_float2(vx, vy);
            } else {
                float2 va;
                if (it == 0) va = make_float2(vx, vy);
                else {
                    va = *(const float2*)&vaccl[2 * t];
                    va.x += vx; va.y += vy;
                }
                *(float2*)&vaccl[2 * t] = va;
                *(float2*)&vls[2 * t]   = va;
            }
        }
        __syncthreads();
        if (it < 2) {
            for (int i = t; i < NJO; i += 576) sl[i] = 0.0f;
            __syncthreads();
        }
    }
}

// ============================================================================
extern "C" void kernel_launch(void* const* d_in, const int* in_sizes, int n_in,
                              void* d_out, int out_size, void* d_ws, size_t ws_size,
                              hipStream_t stream) {
    (void)in_sizes; (void)n_in; (void)out_size; (void)ws_size;

    const float* x = (const float*)d_in[0];  // [B,R,C]
    const float* W = (const float*)d_in[1];  // [R,J,O,C]
    float* out = (float*)d_out;              // [B,J,O,1] fp32

    char* ws = (char*)d_ws;
    const size_t XBYTES = (size_t)NR * NB * NC * 4;   // 18,874,368
    float*  xT = (float*)ws;
    uint32* u  = (uint32*)(ws + XBYTES);              // [B,R,80] f16 pairs

    xpose_kernel<<<dim3(NR / 16, NB / 64), 256, 0, stream>>>(x, xT);
    uhat_kernel<<<NR, 320, 0, stream>>>(xT, W, u);
    routing_kernel<<<NB, 576, 0, stream>>>(u, out);
}